// Round 2
// baseline (740.331 us; speedup 1.0000x reference)
//
#include <hip/hip_runtime.h>
#include <math.h>

// Problem dims (fixed by the reference)
#define ED 16      // EDGE_DIM
#define HD 32      // HIDDEN (== NODE_DIM == in_channels)
#define OD 32      // OUT_DIM
#define KD 1024    // HD*OD
#define OSPLIT 2   // o-halves across gridDim.y
#define OCH 16     // outputs per thread per dispatch half
#define TI 8       // i-tile staged in LDS per iteration

typedef float v2f __attribute__((ext_vector_type(2)));
typedef float v4f __attribute__((ext_vector_type(4)));

// Workspace layout (floats). BN scales folded into weights.
constexpr int OFF_W1 = 0;               // W1fT [32][16]  (transposed, bn1-scaled)
constexpr int OFF_B1 = 512;             // b1f  [32]
constexpr int OFF_BF = 544;             // bfg  [2][512]  idx = s*512 + i*16 + oo  (k = i*32+s*16+oo)
constexpr int OFF_W2 = 1568;            // W2g  [2][512][32] row r=i*16+oo, elem j (bn2-scaled)
constexpr int WS_FLOATS = OFF_W2 + KD * HD;  // 34336 floats = 137344 B

// ---------------------------------------------------------------------------
// Prep: fold BN1/BN2 (eval-mode affine) into weights & biases; write W2 in the
// tiled layout the edge kernel stages from:  W2g[s][i*16+oo][j], k=i*32+s*16+oo
// ---------------------------------------------------------------------------
__global__ void prep_kernel(const float* __restrict__ W1, const float* __restrict__ b1,
                            const float* __restrict__ g1, const float* __restrict__ be1,
                            const float* __restrict__ m1, const float* __restrict__ v1,
                            const float* __restrict__ W2, const float* __restrict__ b2,
                            const float* __restrict__ g2, const float* __restrict__ be2,
                            const float* __restrict__ m2, const float* __restrict__ v2,
                            float* __restrict__ ws)
{
    int t = blockIdx.x * blockDim.x + threadIdx.x;
    int stride = gridDim.x * blockDim.x;
    for (int q = t; q < HD * ED; q += stride) {       // W1fT [c][j]
        int c = q >> 4, j = q & 15;
        float s = g1[c] / sqrtf(v1[c] + 1e-5f);
        ws[OFF_W1 + q] = W1[j * HD + c] * s;
    }
    for (int c = t; c < HD; c += stride) {            // b1f
        float s = g1[c] / sqrtf(v1[c] + 1e-5f);
        ws[OFF_B1 + c] = b1[c] * s + be1[c] - m1[c] * s;
    }
    for (int q = t; q < KD; q += stride) {            // bfg, tiled
        int s_ = q >> 9, r = q & 511;
        int i = r >> 4, oo = r & 15;
        int k = i * HD + s_ * OCH + oo;
        float s = g2[k] / sqrtf(v2[k] + 1e-5f);
        ws[OFF_BF + q] = b2[k] * s + be2[k] - m2[k] * s;
    }
    for (int q = t; q < KD * HD; q += stride) {       // W2g, tiled
        int j = q & 31;
        int r = (q >> 5) & 511;
        int s_ = q >> 14;
        int i = r >> 4, oo = r & 15;
        int k = i * HD + s_ * OCH + oo;
        float s = g2[k] / sqrtf(v2[k] + 1e-5f);
        ws[OFF_W2 + q] = W2[j * KD + k] * s;
    }
}

// ---------------------------------------------------------------------------
// out = x @ root + bias  (initializes all of d_out before edge atomics land)
// ---------------------------------------------------------------------------
__global__ void root_kernel(const float* __restrict__ x, const float* __restrict__ root,
                            const float* __restrict__ bias, float* __restrict__ out, int nN)
{
    int t = blockIdx.x * blockDim.x + threadIdx.x;
    if (t >= nN * OD) return;
    int o = t & (OD - 1);
    int n = t >> 5;
    const float* xr = x + (size_t)n * HD;
    float acc = bias[o];
#pragma unroll
    for (int i = 0; i < HD; ++i)
        acc = fmaf(xr[i], root[i * OD + o], acc);
    out[t] = acc;
}

// ---------------------------------------------------------------------------
// Fused edge kernel v2:
//  - block = 128 threads (2 waves), 2 edges per thread (ME=2) -> 256 edges/block
//  - gridDim.y splits the 32 outputs into 2 halves of 16
//  - W2 (bn-folded, tiled) staged through LDS in 16 KB i-tiles; all lanes read
//    the same row -> conflict-free broadcast, in-order lgkmcnt pipelining
//  - inner dot written as <2 x float> fma -> v_pk_fma_f32 (2x fp32 rate)
//  - invalid-tail threads clamp e->0 and skip only the atomics (barriers stay
//    uniform)
// ---------------------------------------------------------------------------
__global__ __launch_bounds__(128, 3)
void edge_kernel(const float* __restrict__ x, const int* __restrict__ eidx,
                 const float* __restrict__ ea_g, const float* __restrict__ ws,
                 float* __restrict__ out, int nE)
{
    __shared__ __align__(16) float wt[TI * OCH * HD];   // 16 KB
    __shared__ __align__(16) float bfs[512];            // 2 KB

    const int t = threadIdx.x;
    const int s = blockIdx.y;
    const int obase = s * OCH;
    const float* w2g = ws + OFF_W2 + (size_t)s * (512 * HD);
    const float* bfg = ws + OFF_BF + s * 512;

    // stage folded bias half (read after first __syncthreads below)
#pragma unroll
    for (int p = 0; p < 4; ++p) bfs[t + 128 * p] = bfg[t + 128 * p];

    int e0 = blockIdx.x * 256 + t * 2;
    int e1 = e0 + 1;
    bool val0 = e0 < nE, val1 = e1 < nE;
    if (!val0) e0 = 0;
    if (!val1) e1 = 0;

    const int src0 = eidx[e0], dst0 = eidx[nE + e0];
    const int src1 = eidx[e1], dst1 = eidx[nE + e1];

    // ---- layer 1: h = LReLU(ea @ W1f + b1f) for both edges ----
    const float* w1t = ws + OFF_W1;
    const float* b1f = ws + OFF_B1;
    v2f h0[16], h1[16];
    {
        const v4f* ea0 = (const v4f*)(ea_g + (size_t)e0 * ED);
        const v4f* ea1 = (const v4f*)(ea_g + (size_t)e1 * ED);
        v4f a0[4] = {ea0[0], ea0[1], ea0[2], ea0[3]};
        v4f a1[4] = {ea1[0], ea1[1], ea1[2], ea1[3]};
#pragma unroll
        for (int c = 0; c < HD; ++c) {
            const v4f* r4 = (const v4f*)(w1t + c * ED);
            float acc0 = b1f[c], acc1 = acc0;
#pragma unroll
            for (int jq = 0; jq < 4; ++jq) {
                v4f w4 = r4[jq];
                acc0 = fmaf(a0[jq].x, w4.x, acc0);
                acc0 = fmaf(a0[jq].y, w4.y, acc0);
                acc0 = fmaf(a0[jq].z, w4.z, acc0);
                acc0 = fmaf(a0[jq].w, w4.w, acc0);
                acc1 = fmaf(a1[jq].x, w4.x, acc1);
                acc1 = fmaf(a1[jq].y, w4.y, acc1);
                acc1 = fmaf(a1[jq].z, w4.z, acc1);
                acc1 = fmaf(a1[jq].w, w4.w, acc1);
            }
            h0[c >> 1][c & 1] = fmaxf(acc0, 0.01f * acc0);
            h1[c >> 1][c & 1] = fmaxf(acc1, 0.01f * acc1);
        }
    }

    float msg0[OCH], msg1[OCH];
#pragma unroll
    for (int o = 0; o < OCH; ++o) { msg0[o] = 0.f; msg1[o] = 0.f; }

    const float* xr0 = x + (size_t)src0 * HD;
    const float* xr1 = x + (size_t)src1 * HD;

    // ---- layer 2 + message contraction, i-tiled through LDS ----
    for (int it = 0; it < HD / TI; ++it) {
        __syncthreads();   // previous tile fully consumed (and bfs ready, it=0)
        {
            const v4f* gsrc = (const v4f*)(w2g + it * (TI * OCH * HD));
            v4f* ldst = (v4f*)wt;
#pragma unroll
            for (int p = 0; p < 8; ++p) ldst[t + 128 * p] = gsrc[t + 128 * p];
        }
        __syncthreads();

        for (int ii = 0; ii < TI; ++ii) {
            const int i = it * TI + ii;
            float xv0 = xr0[i];
            float xv1 = xr1[i];
            const v4f* bf4 = (const v4f*)(bfs + i * OCH);
            v4f bb[4] = {bf4[0], bf4[1], bf4[2], bf4[3]};
            const float* brow = wt + ii * (OCH * HD);
#pragma unroll
            for (int oo = 0; oo < OCH; ++oo) {
                const v4f* r4 = (const v4f*)(brow + oo * HD);
                float bfv = bb[oo >> 2][oo & 3];
                v2f a0 = {bfv, 0.f};
                v2f a1 = {bfv, 0.f};
#pragma unroll
                for (int q = 0; q < 8; ++q) {
                    v4f w4 = r4[q];
                    a0 = __builtin_elementwise_fma(w4.lo, h0[2 * q], a0);
                    a1 = __builtin_elementwise_fma(w4.lo, h1[2 * q], a1);
                    a0 = __builtin_elementwise_fma(w4.hi, h0[2 * q + 1], a0);
                    a1 = __builtin_elementwise_fma(w4.hi, h1[2 * q + 1], a1);
                }
                float s0 = a0.x + a0.y;
                float s1 = a1.x + a1.y;
                float w0 = fmaxf(s0, 0.01f * s0);
                float w1v = fmaxf(s1, 0.01f * s1);
                msg0[oo] = fmaf(xv0, w0, msg0[oo]);
                msg1[oo] = fmaf(xv1, w1v, msg1[oo]);
            }
        }
    }

    float* o0 = out + (size_t)dst0 * OD + obase;
    float* o1 = out + (size_t)dst1 * OD + obase;
    if (val0) {
#pragma unroll
        for (int oo = 0; oo < OCH; ++oo) atomicAdd(o0 + oo, msg0[oo]);
    }
    if (val1) {
#pragma unroll
        for (int oo = 0; oo < OCH; ++oo) atomicAdd(o1 + oo, msg1[oo]);
    }
}

// ---------------------------------------------------------------------------
// Fallback (ws too small): correctness path only.
// ---------------------------------------------------------------------------
__global__ __launch_bounds__(64)
void edge_kernel_raw(const float* __restrict__ x, const int* __restrict__ eidx,
                     const float* __restrict__ ea_g,
                     const float* __restrict__ W1, const float* __restrict__ b1,
                     const float* __restrict__ g1, const float* __restrict__ be1,
                     const float* __restrict__ m1, const float* __restrict__ v1,
                     const float* __restrict__ W2, const float* __restrict__ b2,
                     const float* __restrict__ g2, const float* __restrict__ be2,
                     const float* __restrict__ m2, const float* __restrict__ v2,
                     float* __restrict__ out, int nE)
{
    int e = blockIdx.x * 64 + threadIdx.x;
    if (e >= nE) return;
    const int obase = blockIdx.y * OCH;

    int src = eidx[e];
    int dst = eidx[nE + e];

    float ea[ED];
#pragma unroll
    for (int j = 0; j < ED; ++j) ea[j] = ea_g[(size_t)e * ED + j];

    float h[HD];
#pragma unroll
    for (int c = 0; c < HD; ++c) {
        float acc = b1[c];
#pragma unroll
        for (int j = 0; j < ED; ++j) acc = fmaf(ea[j], W1[j * HD + c], acc);
        float s = g1[c] / sqrtf(v1[c] + 1e-5f);
        acc = (acc - m1[c]) * s + be1[c];
        h[c] = fmaxf(acc, 0.01f * acc);
    }

    float msg[OCH];
#pragma unroll
    for (int o = 0; o < OCH; ++o) msg[o] = 0.f;

    const float* xj = x + (size_t)src * HD;
    for (int i = 0; i < HD; ++i) {
        float xv = xj[i];
#pragma unroll
        for (int oo = 0; oo < OCH; ++oo) {
            int k = i * OD + obase + oo;
            float acc = b2[k];
#pragma unroll
            for (int j = 0; j < HD; ++j) acc = fmaf(h[j], W2[j * KD + k], acc);
            float s = g2[k] / sqrtf(v2[k] + 1e-5f);
            acc = (acc - m2[k]) * s + be2[k];
            float w = fmaxf(acc, 0.01f * acc);
            msg[oo] = fmaf(xv, w, msg[oo]);
        }
    }

    float* op = out + (size_t)dst * OD + obase;
#pragma unroll
    for (int oo = 0; oo < OCH; ++oo) atomicAdd(op + oo, msg[oo]);
}

// ---------------------------------------------------------------------------
extern "C" void kernel_launch(void* const* d_in, const int* in_sizes, int n_in,
                              void* d_out, int out_size, void* d_ws, size_t ws_size,
                              hipStream_t stream)
{
    const float* x    = (const float*)d_in[0];
    const int*   eidx = (const int*)  d_in[1];
    const float* ea   = (const float*)d_in[2];
    // d_in[3] = batch (unused)
    const float* W1   = (const float*)d_in[4];
    const float* b1   = (const float*)d_in[5];
    const float* g1   = (const float*)d_in[6];
    const float* be1  = (const float*)d_in[7];
    const float* m1   = (const float*)d_in[8];
    const float* v1   = (const float*)d_in[9];
    const float* W2   = (const float*)d_in[10];
    const float* b2   = (const float*)d_in[11];
    const float* g2   = (const float*)d_in[12];
    const float* be2  = (const float*)d_in[13];
    const float* m2   = (const float*)d_in[14];
    const float* v2   = (const float*)d_in[15];
    const float* root = (const float*)d_in[16];
    const float* bias = (const float*)d_in[17];
    float* out = (float*)d_out;

    int nN = in_sizes[0] / HD;
    int nE = in_sizes[2] / ED;

    root_kernel<<<dim3((nN * OD + 255) / 256), 256, 0, stream>>>(x, root, bias, out, nN);

    bool prepped = ws_size >= (size_t)WS_FLOATS * sizeof(float);
    if (prepped) {
        float* ws = (float*)d_ws;
        prep_kernel<<<128, 256, 0, stream>>>(W1, b1, g1, be1, m1, v1,
                                             W2, b2, g2, be2, m2, v2, ws);
        int nblk = (nE + 255) / 256;
        edge_kernel<<<dim3(nblk, OSPLIT), 128, 0, stream>>>(x, eidx, ea, ws, out, nE);
    } else {
        edge_kernel_raw<<<dim3((nE + 63) / 64, OSPLIT), 64, 0, stream>>>(
            x, eidx, ea, W1, b1, g1, be1, m1, v1,
            W2, b2, g2, be2, m2, v2, out, nE);
    }
}

// Round 3
// 270.418 us; speedup vs baseline: 2.7377x; 2.7377x over previous
//
#include <hip/hip_runtime.h>
#include <math.h>

// Problem dims (fixed by the reference)
#define ED 16      // EDGE_DIM
#define HD 32      // HIDDEN (== NODE_DIM == in_channels)
#define OD 32      // OUT_DIM
#define KD 1024    // HD*OD
#define EPB 256    // edges per block
#define NW 4       // waves per block
#define TPW 4      // 16-edge tiles per wave

typedef float  f32x4  __attribute__((ext_vector_type(4)));
typedef float  v4f    __attribute__((ext_vector_type(4)));
typedef short  bf16x8 __attribute__((ext_vector_type(8)));

// Workspace layout (byte offsets; all 16B aligned)
//  [0)      W1fT   512 f32   [c][j] transposed, bn1-scaled
//  [2048)   b1f     32 f32
//  [2176)   bfold 1024 f32   folded layer-2 bias, natural k order
//  [6272)   wsAhi 32768 bf16 W2fT hi, frag-linear: q = g*512 + lane*8 + idx
//                             -> value W2fT[k=g*16+(lane&15)][j=(lane>>4)*8+idx]
//  [71808)  wsAlo 32768 bf16 W2fT lo, same order
constexpr size_t WS_BYTES = 137344;

__device__ inline void bf16_split(float v, unsigned short& hi, unsigned short& lo) {
    unsigned int b = __float_as_uint(v);
    hi = (unsigned short)(b >> 16);
    float hif = __uint_as_float((unsigned int)hi << 16);
    float lof = v - hif;
    lo = (unsigned short)(__float_as_uint(lof) >> 16);
}

// ---------------------------------------------------------------------------
// Prep: fold BN into weights/biases; write W2fT as hi/lo bf16 in the exact
// per-lane fragment-linear order the edge kernel's A-operand loads use.
// ---------------------------------------------------------------------------
__global__ void prep_kernel(const float* __restrict__ W1, const float* __restrict__ b1,
                            const float* __restrict__ g1, const float* __restrict__ be1,
                            const float* __restrict__ m1, const float* __restrict__ v1,
                            const float* __restrict__ W2, const float* __restrict__ b2,
                            const float* __restrict__ g2, const float* __restrict__ be2,
                            const float* __restrict__ m2, const float* __restrict__ v2,
                            unsigned char* __restrict__ wsb)
{
    float* w1t = (float*)(wsb);
    float* b1f = (float*)(wsb + 2048);
    float* bf  = (float*)(wsb + 2176);
    unsigned short* ahi = (unsigned short*)(wsb + 6272);
    unsigned short* alo = (unsigned short*)(wsb + 71808);

    int t = blockIdx.x * blockDim.x + threadIdx.x;
    int stride = gridDim.x * blockDim.x;

    for (int q = t; q < HD * ED; q += stride) {       // W1fT [c][j]
        int c = q >> 4, j = q & 15;
        float s = g1[c] / sqrtf(v1[c] + 1e-5f);
        w1t[q] = W1[j * HD + c] * s;
    }
    for (int c = t; c < HD; c += stride) {
        float s = g1[c] / sqrtf(v1[c] + 1e-5f);
        b1f[c] = b1[c] * s + be1[c] - m1[c] * s;
    }
    for (int k = t; k < KD; k += stride) {
        float s = g2[k] / sqrtf(v2[k] + 1e-5f);
        bf[k] = b2[k] * s + be2[k] - m2[k] * s;
    }
    for (int q = t; q < KD * HD; q += stride) {       // frag-linear W2fT hi/lo
        int g = q >> 9;
        int r = q & 511;
        int lane = r >> 3, idx = r & 7;
        int m = lane & 15, quad = lane >> 4;
        int k = g * 16 + m;
        int j = quad * 8 + idx;
        float s = g2[k] / sqrtf(v2[k] + 1e-5f);
        float v = W2[j * KD + k] * s;
        unsigned short hi, lo;
        bf16_split(v, hi, lo);
        ahi[q] = hi;
        alo[q] = lo;
    }
}

// ---------------------------------------------------------------------------
// out = x @ root + bias  (initializes all of d_out before edge atomics land)
// ---------------------------------------------------------------------------
__global__ void root_kernel(const float* __restrict__ x, const float* __restrict__ root,
                            const float* __restrict__ bias, float* __restrict__ out, int nN)
{
    int t = blockIdx.x * blockDim.x + threadIdx.x;
    if (t >= nN * OD) return;
    int o = t & (OD - 1);
    int n = t >> 5;
    const float* xr = x + (size_t)n * HD;
    float acc = bias[o];
#pragma unroll
    for (int i = 0; i < HD; ++i)
        acc = fmaf(xr[i], root[i * OD + o], acc);
    out[t] = acc;
}

// ---------------------------------------------------------------------------
// Fused edge kernel v3 (MFMA):
//  Phase 1: one edge/thread -> h = LReLU(ea@W1f+b1f) fp32, split to bf16
//           hi/lo, stored in LDS in B-fragment order (dense [edge][j]).
//  Phase 2: GEMM orientation C[k][edge] = W2fT[k][j] @ h[j][edge]:
//           A = weight frags (global dwordx4/lane, L2-hot, hi+lo),
//           B = h frags (8 ds_read_b128 once, held in VGPRs),
//           C init = folded bias; 3 MFMAs per C (split-bf16 compensation);
//           epilogue: LReLU + msg[edge][o] += x[src(edge),i] * w  (one x
//           scalar per lane per i since C cols = edges).
//  2 barriers per block total; 37 KB LDS -> 4 blocks/CU.
// ---------------------------------------------------------------------------
__global__ __launch_bounds__(256)
void edge_kernel(const float* __restrict__ x, const int* __restrict__ eidx,
                 const float* __restrict__ ea_g, const unsigned char* __restrict__ wsb,
                 float* __restrict__ out, int nE)
{
    __shared__ __align__(16) float w1t[512];
    __shared__ __align__(16) float b1s[32];
    __shared__ __align__(16) unsigned short hHi[EPB * HD];  // [edge][j]
    __shared__ __align__(16) unsigned short hLo[EPB * HD];
    __shared__ int srcS[EPB];
    __shared__ int dstS[EPB];

    const int t = threadIdx.x;
    const float* wsW1 = (const float*)(wsb);
    const float* wsB1 = (const float*)(wsb + 2048);
    const float* wsBf = (const float*)(wsb + 2176);
    const unsigned short* wsAhi = (const unsigned short*)(wsb + 6272);
    const unsigned short* wsAlo = (const unsigned short*)(wsb + 71808);

    // stage W1fT + b1f
    if (t < 128)      ((v4f*)w1t)[t] = ((const v4f*)wsW1)[t];
    else if (t < 136) ((v4f*)b1s)[t - 128] = ((const v4f*)wsB1)[t - 128];

    int e = blockIdx.x * EPB + t;
    int ec = (e < nE) ? e : (nE - 1);
    srcS[t] = eidx[ec];
    dstS[t] = eidx[nE + ec];

    const v4f* eap = (const v4f*)(ea_g + (size_t)ec * ED);
    v4f a0 = eap[0], a1 = eap[1], a2 = eap[2], a3 = eap[3];

    __syncthreads();   // w1t/b1s ready

    // ---- layer 1 + bf16 hi/lo split into LDS ----
#pragma unroll
    for (int c = 0; c < HD; ++c) {
        const v4f* r4 = (const v4f*)(w1t + c * ED);
        v4f w0 = r4[0], w1 = r4[1], w2 = r4[2], w3 = r4[3];
        float acc = b1s[c];
        acc = fmaf(a0.x, w0.x, acc); acc = fmaf(a0.y, w0.y, acc);
        acc = fmaf(a0.z, w0.z, acc); acc = fmaf(a0.w, w0.w, acc);
        acc = fmaf(a1.x, w1.x, acc); acc = fmaf(a1.y, w1.y, acc);
        acc = fmaf(a1.z, w1.z, acc); acc = fmaf(a1.w, w1.w, acc);
        acc = fmaf(a2.x, w2.x, acc); acc = fmaf(a2.y, w2.y, acc);
        acc = fmaf(a2.z, w2.z, acc); acc = fmaf(a2.w, w2.w, acc);
        acc = fmaf(a3.x, w3.x, acc); acc = fmaf(a3.y, w3.y, acc);
        acc = fmaf(a3.z, w3.z, acc); acc = fmaf(a3.w, w3.w, acc);
        acc = fmaxf(acc, 0.01f * acc);
        unsigned short hi, lo;
        bf16_split(acc, hi, lo);
        hHi[t * HD + c] = hi;
        hLo[t * HD + c] = lo;
    }
    __syncthreads();

    // ---- phase 2: MFMA GEMM + fused contraction ----
    const int wave = t >> 6;
    const int lane = t & 63;
    const int n = lane & 15;       // C column = edge within tile
    const int quad = lane >> 4;
    const int ebase = wave * 64;   // wave's first edge in block

    bf16x8 bHi[TPW], bLo[TPW];
#pragma unroll
    for (int tt = 0; tt < TPW; ++tt) {
        int edge = ebase + tt * 16 + n;
        bHi[tt] = *(const bf16x8*)(hHi + edge * HD + quad * 8);
        bLo[tt] = *(const bf16x8*)(hLo + edge * HD + quad * 8);
    }

    int xsrc[TPW], xdst[TPW];
    bool evalid[TPW];
#pragma unroll
    for (int tt = 0; tt < TPW; ++tt) {
        int le = ebase + tt * 16 + n;
        evalid[tt] = (blockIdx.x * EPB + le) < nE;
        xsrc[tt] = srcS[le];
        xdst[tt] = dstS[le];
    }

    f32x4 msg[TPW][2];
#pragma unroll
    for (int tt = 0; tt < TPW; ++tt)
#pragma unroll
        for (int oh = 0; oh < 2; ++oh)
            msg[tt][oh] = (f32x4){0.f, 0.f, 0.f, 0.f};

    for (int i = 0; i < HD; ++i) {
        float xv[TPW];
#pragma unroll
        for (int tt = 0; tt < TPW; ++tt)
            xv[tt] = x[(size_t)xsrc[tt] * HD + i];
#pragma unroll
        for (int oh = 0; oh < 2; ++oh) {
            const int g = i * 2 + oh;   // k-group: k = g*16 + m
            bf16x8 aHi = *(const bf16x8*)(wsAhi + g * 512 + lane * 8);
            bf16x8 aLo = *(const bf16x8*)(wsAlo + g * 512 + lane * 8);
            f32x4 bias4 = *(const f32x4*)(wsBf + g * 16 + quad * 4);
#pragma unroll
            for (int tt = 0; tt < TPW; ++tt) {
                f32x4 c = bias4;
                c = __builtin_amdgcn_mfma_f32_16x16x32_bf16(aLo, bHi[tt], c, 0, 0, 0);
                c = __builtin_amdgcn_mfma_f32_16x16x32_bf16(aHi, bLo[tt], c, 0, 0, 0);
                c = __builtin_amdgcn_mfma_f32_16x16x32_bf16(aHi, bHi[tt], c, 0, 0, 0);
#pragma unroll
                for (int r = 0; r < 4; ++r) {
                    float w = c[r];
                    w = fmaxf(w, 0.01f * w);                 // LeakyReLU
                    msg[tt][oh][r] = fmaf(xv[tt], w, msg[tt][oh][r]);
                }
            }
        }
    }

    // ---- scatter: out[dst][o], o = oh*16 + quad*4 + r ----
#pragma unroll
    for (int tt = 0; tt < TPW; ++tt) {
        if (!evalid[tt]) continue;
        float* op = out + (size_t)xdst[tt] * OD;
#pragma unroll
        for (int oh = 0; oh < 2; ++oh)
#pragma unroll
            for (int r = 0; r < 4; ++r)
                atomicAdd(op + oh * 16 + quad * 4 + r, msg[tt][oh][r]);
    }
}

// ---------------------------------------------------------------------------
// Fallback (ws too small): correctness path only (VALU, raw weights).
// ---------------------------------------------------------------------------
__global__ __launch_bounds__(64)
void edge_kernel_raw(const float* __restrict__ x, const int* __restrict__ eidx,
                     const float* __restrict__ ea_g,
                     const float* __restrict__ W1, const float* __restrict__ b1,
                     const float* __restrict__ g1, const float* __restrict__ be1,
                     const float* __restrict__ m1, const float* __restrict__ v1,
                     const float* __restrict__ W2, const float* __restrict__ b2,
                     const float* __restrict__ g2, const float* __restrict__ be2,
                     const float* __restrict__ m2, const float* __restrict__ v2,
                     float* __restrict__ out, int nE)
{
    int e = blockIdx.x * 64 + threadIdx.x;
    if (e >= nE) return;
    const int obase = blockIdx.y * 16;

    int src = eidx[e];
    int dst = eidx[nE + e];

    float ea[ED];
#pragma unroll
    for (int j = 0; j < ED; ++j) ea[j] = ea_g[(size_t)e * ED + j];

    float h[HD];
#pragma unroll
    for (int c = 0; c < HD; ++c) {
        float acc = b1[c];
#pragma unroll
        for (int j = 0; j < ED; ++j) acc = fmaf(ea[j], W1[j * HD + c], acc);
        float s = g1[c] / sqrtf(v1[c] + 1e-5f);
        acc = (acc - m1[c]) * s + be1[c];
        h[c] = fmaxf(acc, 0.01f * acc);
    }

    float msg[16];
#pragma unroll
    for (int o = 0; o < 16; ++o) msg[o] = 0.f;

    const float* xj = x + (size_t)src * HD;
    for (int i = 0; i < HD; ++i) {
        float xv = xj[i];
#pragma unroll
        for (int oo = 0; oo < 16; ++oo) {
            int k = i * OD + obase + oo;
            float acc = b2[k];
#pragma unroll
            for (int j = 0; j < HD; ++j) acc = fmaf(h[j], W2[j * KD + k], acc);
            float s = g2[k] / sqrtf(v2[k] + 1e-5f);
            acc = (acc - m2[k]) * s + be2[k];
            float w = fmaxf(acc, 0.01f * acc);
            msg[oo] = fmaf(xv, w, msg[oo]);
        }
    }

    float* op = out + (size_t)dst * OD + obase;
#pragma unroll
    for (int oo = 0; oo < 16; ++oo) atomicAdd(op + oo, msg[oo]);
}

// ---------------------------------------------------------------------------
extern "C" void kernel_launch(void* const* d_in, const int* in_sizes, int n_in,
                              void* d_out, int out_size, void* d_ws, size_t ws_size,
                              hipStream_t stream)
{
    const float* x    = (const float*)d_in[0];
    const int*   eidx = (const int*)  d_in[1];
    const float* ea   = (const float*)d_in[2];
    // d_in[3] = batch (unused)
    const float* W1   = (const float*)d_in[4];
    const float* b1   = (const float*)d_in[5];
    const float* g1   = (const float*)d_in[6];
    const float* be1  = (const float*)d_in[7];
    const float* m1   = (const float*)d_in[8];
    const float* v1   = (const float*)d_in[9];
    const float* W2   = (const float*)d_in[10];
    const float* b2   = (const float*)d_in[11];
    const float* g2   = (const float*)d_in[12];
    const float* be2  = (const float*)d_in[13];
    const float* m2   = (const float*)d_in[14];
    const float* v2   = (const float*)d_in[15];
    const float* root = (const float*)d_in[16];
    const float* bias = (const float*)d_in[17];
    float* out = (float*)d_out;

    int nN = in_sizes[0] / HD;
    int nE = in_sizes[2] / ED;

    root_kernel<<<dim3((nN * OD + 255) / 256), 256, 0, stream>>>(x, root, bias, out, nN);

    if (ws_size >= WS_BYTES) {
        unsigned char* wsb = (unsigned char*)d_ws;
        prep_kernel<<<128, 256, 0, stream>>>(W1, b1, g1, be1, m1, v1,
                                             W2, b2, g2, be2, m2, v2, wsb);
        int nblk = (nE + EPB - 1) / EPB;
        edge_kernel<<<dim3(nblk), 256, 0, stream>>>(x, eidx, ea, wsb, out, nE);
    } else {
        edge_kernel_raw<<<dim3((nE + 63) / 64, 2), 64, 0, stream>>>(
            x, eidx, ea, W1, b1, g1, be1, m1, v1,
            W2, b2, g2, be2, m2, v2, out, nE);
    }
}